// Round 1
// baseline (345.220 us; speedup 1.0000x reference)
//
#include <hip/hip_runtime.h>
#include <hip/hip_bf16.h>
#include <stdint.h>

// ---------------- problem constants ----------------
#define T_  4
#define B_  4
#define C_  512
#define N_  1024       // H*W
#define NH_ 8
#define HD_ 64
#define NP_ 16384      // T*B*N  (columns of the big GEMMs)
#define EPS_ 1e-5f

typedef __bf16 bf16_t;
typedef __bf16 bf16x8 __attribute__((ext_vector_type(8)));
typedef float  f32x4  __attribute__((ext_vector_type(4)));
typedef unsigned long long u64;

// ---------------- workspace layout (bytes) ----------------
// total = 74,465,280 B (~71 MB)
#define XS_OFF   0ULL                      // bf16 XsT[16384][512]   (spikes of x, transposed)
#define AHI_OFF  16777216ULL               // bf16 [1536][512]  stacked Wq/Wk/Wv hi
#define ALO_OFF  18350080ULL               // bf16 [1536][512]  lo
#define PHI_OFF  19922944ULL               // bf16 [512][512]   Wp hi
#define PLO_OFF  20447232ULL               // bf16 [512][512]   Wp lo
#define SC_OFF   20971520ULL               // f32 [1536] BN scale (stacked q,k,v)
#define SH_OFF   20977664ULL               // f32 [1536] BN shift
#define PSC_OFF  20983808ULL               // f32 [512]
#define PSH_OFF  20985856ULL               // f32 [512]  (includes bp folded)
#define Y1_OFF   20987904ULL               // f32 [512][16384]  (one branch at a time)
#define QB_OFF   54542336ULL               // u64 [16][8][64][16] q spike bits (bits over n)
#define KB_OFF   55590912ULL
#define VB_OFF   56639488ULL
#define OST_OFF  57688064ULL               // bf16 OsT[16384][512]  attn-lif spikes, transposed

// =====================================================================
// K0: weight split (hi/lo bf16) + BN constant folding
// =====================================================================
__global__ __launch_bounds__(256) void prep_kernel(
    const float* __restrict__ Wq, const float* __restrict__ Wk,
    const float* __restrict__ Wv, const float* __restrict__ Wp,
    const float* __restrict__ qg, const float* __restrict__ qb, const float* __restrict__ qm, const float* __restrict__ qv,
    const float* __restrict__ kg, const float* __restrict__ kb, const float* __restrict__ km, const float* __restrict__ kv,
    const float* __restrict__ vg, const float* __restrict__ vb, const float* __restrict__ vm, const float* __restrict__ vv,
    const float* __restrict__ bp,
    const float* __restrict__ pg, const float* __restrict__ pb, const float* __restrict__ pm, const float* __restrict__ pv,
    bf16_t* __restrict__ Ahi, bf16_t* __restrict__ Alo,
    bf16_t* __restrict__ Phi, bf16_t* __restrict__ Plo,
    float* __restrict__ scale, float* __restrict__ shift,
    float* __restrict__ pscale, float* __restrict__ pshift)
{
    const int i0 = blockIdx.x * 256 + threadIdx.x;
    const int stride = gridDim.x * 256;
    // stacked qkv weights: rows 0-511 Wq, 512-1023 Wk, 1024-1535 Wv ; A[r][c] = W[r&511][c]
    for (int idx = i0; idx < 1536 * 512; idx += stride) {
        int r = idx >> 9;
        int br = r >> 9;
        const float* W = (br == 0) ? Wq : (br == 1) ? Wk : Wv;
        float w = W[((r & 511) << 9) + (idx & 511)];
        bf16_t h = (bf16_t)w;
        Ahi[idx] = h;
        Alo[idx] = (bf16_t)(w - (float)h);
    }
    for (int idx = i0; idx < 512 * 512; idx += stride) {
        float w = Wp[idx];
        bf16_t h = (bf16_t)w;
        Phi[idx] = h;
        Plo[idx] = (bf16_t)(w - (float)h);
    }
    for (int idx = i0; idx < 1536; idx += stride) {
        int br = idx >> 9, d = idx & 511;
        const float* g  = (br == 0) ? qg : (br == 1) ? kg : vg;
        const float* bb = (br == 0) ? qb : (br == 1) ? kb : vb;
        const float* mm = (br == 0) ? qm : (br == 1) ? km : vm;
        const float* vr = (br == 0) ? qv : (br == 1) ? kv : vv;
        float sc = g[d] / sqrtf(vr[d] + EPS_);
        scale[idx] = sc;
        shift[idx] = bb[d] - mm[d] * sc;
    }
    for (int idx = i0; idx < 512; idx += stride) {
        float sc = pg[idx] / sqrtf(pv[idx] + EPS_);
        pscale[idx] = sc;
        pshift[idx] = (bp[idx] - pm[idx]) * sc + pb[idx];
    }
}

// =====================================================================
// K1: proj_lif on x  ->  spikes, stored transposed XsT[n'][c] bf16
//     n' = (t*B+b)*N + n.  Thread owns (16 consecutive c, one n), LIF over t.
// =====================================================================
__global__ __launch_bounds__(256) void lif_x_kernel(const float* __restrict__ x,
                                                    bf16_t* __restrict__ xsT)
{
    const int tid = threadIdx.x;
    const int n  = blockIdx.x * 64 + (tid & 63);
    const int c0 = blockIdx.y * 64 + (tid >> 6) * 16;
    const int b  = blockIdx.z;
    float v[16];
#pragma unroll
    for (int k = 0; k < 16; ++k) v[k] = 0.f;

    for (int t = 0; t < T_; ++t) {
        bf16x8 s0, s1;
#pragma unroll
        for (int k = 0; k < 16; ++k) {
            float xv = x[(size_t)((t * B_ + b) * C_ + (c0 + k)) * N_ + n];
            float vn = v[k] + (xv - v[k]) * 0.5f;           // tau = 2
            bool s = (vn >= 1.0f);
            v[k] = s ? 0.0f : vn;                           // hard reset
            bf16_t sp = s ? (bf16_t)1.0f : (bf16_t)0.0f;
            if (k < 8) s0[k] = sp; else s1[k - 8] = sp;
        }
        bf16_t* dst = xsT + (size_t)((t * B_ + b) * N_ + n) * C_ + c0;
        *(bf16x8*)dst = s0;
        *(bf16x8*)(dst + 8) = s1;
    }
}

// =====================================================================
// GEMM: out[m][n'] = sum_c (Ahi+Alo)[m][c] * B[n'][c]   (B given pre-transposed)
// 128x128 tile, BK=32, 4 waves (2x2 of 64x64), 16x16x32 bf16 MFMA,
// global_load_lds width-16 staging (m97 structure).
// MODE 0: out = f32 [512][16384], y = acc*scale[r]+shift[r]  (BN folded)
// MODE 1: out = d_out [T*B][C][N]; col gc -> (tb=gc>>10, n=gc&1023)
// =====================================================================
template <int MODE>
__global__ __launch_bounds__(256) void gemm_spk(
    const bf16_t* __restrict__ Ahi, const bf16_t* __restrict__ Alo,
    const bf16_t* __restrict__ Bm,
    const float* __restrict__ scale, const float* __restrict__ shift,
    float* __restrict__ out)
{
    __shared__ bf16_t AsH[128 * 32];
    __shared__ bf16_t AsL[128 * 32];
    __shared__ bf16_t Bs [128 * 32];

    const int tid  = threadIdx.x;
    const int lane = tid & 63;
    const int wv   = tid >> 6;
    const int wr   = wv >> 1, wc = wv & 1;
    const int m0   = blockIdx.y * 128;
    const int n0   = blockIdx.x * 128;

    f32x4 acc[4][4];
#pragma unroll
    for (int i = 0; i < 4; ++i)
#pragma unroll
        for (int j = 0; j < 4; ++j) acc[i][j] = f32x4{0.f, 0.f, 0.f, 0.f};

    const int frow = lane & 15;
    const int koff = (lane >> 4) << 3;

    for (int kk = 0; kk < 512; kk += 32) {
#pragma unroll
        for (int s = 0; s < 2; ++s) {
            int idx = s * 256 + tid;            // 0..511 : 16B segment id
            int row = idx >> 2;
            int kc  = (idx & 3) << 3;
            size_t goffA = (size_t)(m0 + row) * 512 + kk + kc;
            size_t goffB = (size_t)(n0 + row) * 512 + kk + kc;
            int ldsoff = (s * 256 + wv * 64) * 8;   // wave-uniform base (elements)
            __builtin_amdgcn_global_load_lds((const __attribute__((address_space(1))) void*)(Ahi + goffA),
                                             (__attribute__((address_space(3))) void*)(AsH + ldsoff), 16, 0, 0);
            __builtin_amdgcn_global_load_lds((const __attribute__((address_space(1))) void*)(Alo + goffA),
                                             (__attribute__((address_space(3))) void*)(AsL + ldsoff), 16, 0, 0);
            __builtin_amdgcn_global_load_lds((const __attribute__((address_space(1))) void*)(Bm + goffB),
                                             (__attribute__((address_space(3))) void*)(Bs + ldsoff), 16, 0, 0);
        }
        __syncthreads();

        bf16x8 ah[4], al[4], bb[4];
#pragma unroll
        for (int mi = 0; mi < 4; ++mi) {
            ah[mi] = *(const bf16x8*)&AsH[(wr * 64 + mi * 16 + frow) * 32 + koff];
            al[mi] = *(const bf16x8*)&AsL[(wr * 64 + mi * 16 + frow) * 32 + koff];
        }
#pragma unroll
        for (int ni = 0; ni < 4; ++ni)
            bb[ni] = *(const bf16x8*)&Bs[(wc * 64 + ni * 16 + frow) * 32 + koff];

#pragma unroll
        for (int mi = 0; mi < 4; ++mi)
#pragma unroll
            for (int ni = 0; ni < 4; ++ni) {
                acc[mi][ni] = __builtin_amdgcn_mfma_f32_16x16x32_bf16(ah[mi], bb[ni], acc[mi][ni], 0, 0, 0);
                acc[mi][ni] = __builtin_amdgcn_mfma_f32_16x16x32_bf16(al[mi], bb[ni], acc[mi][ni], 0, 0, 0);
            }
        __syncthreads();
    }

    // epilogue: D lane mapping col = lane&15, row = (lane>>4)*4 + r
#pragma unroll
    for (int mi = 0; mi < 4; ++mi)
#pragma unroll
        for (int ni = 0; ni < 4; ++ni)
#pragma unroll
            for (int r = 0; r < 4; ++r) {
                int gr = m0 + wr * 64 + mi * 16 + (lane >> 4) * 4 + r;
                int gc = n0 + wc * 64 + ni * 16 + (lane & 15);
                float vout = acc[mi][ni][r] * scale[gr] + shift[gr];
                if (MODE == 0) {
                    out[(size_t)gr * NP_ + gc] = vout;
                } else {
                    int tb = gc >> 10, nn = gc & 1023;
                    out[((size_t)(tb * C_ + gr)) * N_ + nn] = vout;
                }
            }
}

// =====================================================================
// K3: LIF over t on BN'd GEMM output of ONE branch, emit spike bits
//     bits[(tb*8+h)*64+d][w] : bit i of word w  <->  n = w*64+i
// =====================================================================
__global__ __launch_bounds__(256) void lif_bits_kernel(const float* __restrict__ Y1,
                                                       u64* __restrict__ dst)
{
    const int tid = threadIdx.x;
    const int n = blockIdx.x * 256 + tid;
    const int b = blockIdx.y;
    const int r = blockIdx.z;            // channel 0..511 within branch
    const int h = r >> 6, d = r & 63;
    const int w = n >> 6;
    const int lane = tid & 63;

    const float* src = Y1 + (size_t)r * NP_;
    float v = 0.f;
    for (int t = 0; t < T_; ++t) {
        float val = src[((t * B_ + b) << 10) + n];
        v = v + (val - v) * 0.5f;
        bool s = (v >= 1.0f);
        if (s) v = 0.f;
        u64 mask = __ballot(s);
        if (lane == 0)
            dst[((size_t)((t * B_ + b) * NH_ + h) * 64 + d) * 16 + w] = mask;
    }
}

// =====================================================================
// K5: attention via associativity + bit tricks, fused attn_lif.
//  per (t,b,h):  M2 = K^T V  (popcount over n-bit words, *0.125 folded, exact)
//                O[n][d] = sum_d1 qbit(n,d1) * M2f[d1][d]   (exact fp32)
//                attn-LIF over t (v_th=0.5)  -> spike -> OsT[n'][c]
//  block = (n-chunk of 64, h, b); thread owns (d = tid>>2, 16 n) across t.
// =====================================================================
__global__ __launch_bounds__(256) void attn_kernel(const u64* __restrict__ qbit,
                                                   const u64* __restrict__ kbit,
                                                   const u64* __restrict__ vbit,
                                                   bf16_t* __restrict__ osT)
{
    __shared__ u64   Kb[64][17];     // +1 pad: spread d-rows across banks
    __shared__ u64   Vb[64][17];
    __shared__ float M2f[64][64];
    __shared__ u64   Qw[64];
    __shared__ bf16_t ot[64][72];    // [c_local][n_local], row stride 144B (16B aligned)

    const int tid = threadIdx.x;
    const int nc = blockIdx.x;       // n-chunk (one 64-bit word)
    const int h  = blockIdx.y;
    const int b  = blockIdx.z;
    const int dq = tid >> 2;         // 0..63 : d1 for M2 phase, d for O phase
    const int l2 = tid & 3;
    const int sh = l2 * 16;          // n-offset within word for O phase

    float v[16];
#pragma unroll
    for (int j = 0; j < 16; ++j) v[j] = 0.f;

    for (int t = 0; t < T_; ++t) {
        const int tb = t * B_ + b;
        const u64* kbase = kbit + (size_t)(tb * NH_ + h) * 64 * 16;
        const u64* vbase = vbit + (size_t)(tb * NH_ + h) * 64 * 16;
        for (int i = tid; i < 1024; i += 256) {
            Kb[i >> 4][i & 15] = kbase[i];
            Vb[i >> 4][i & 15] = vbase[i];
        }
        if (tid < 64) Qw[tid] = qbit[((size_t)(tb * NH_ + h) * 64 + tid) * 16 + nc];
        __syncthreads();

        // ---- M2 = K^T V via popcount (thread: d1=dq, d2 = l2+4*jj) ----
        int cnt[16];
#pragma unroll
        for (int jj = 0; jj < 16; ++jj) cnt[jj] = 0;
        for (int w = 0; w < 16; ++w) {
            u64 kw = Kb[dq][w];
#pragma unroll
            for (int jj = 0; jj < 16; ++jj)
                cnt[jj] += __popcll(kw & Vb[l2 + 4 * jj][w]);
        }
#pragma unroll
        for (int jj = 0; jj < 16; ++jj)
            M2f[dq][l2 + 4 * jj] = (float)cnt[jj] * 0.125f;   // fold *0.125 (exact)
        __syncthreads();

        // ---- O = Q @ M2 for this n-word; thread: d=dq, n = nc*64+sh+j ----
        float acc[16];
#pragma unroll
        for (int j = 0; j < 16; ++j) acc[j] = 0.f;
        for (int dd = 0; dd < 64; ++dd) {
            unsigned q16 = (unsigned)(Qw[dd] >> sh) & 0xFFFFu;
            float m2 = M2f[dd][dq];
#pragma unroll
            for (int j = 0; j < 16; ++j)
                acc[j] += ((q16 >> j) & 1u) ? m2 : 0.f;
        }

        // ---- attn LIF (v_th = 0.5), spikes to LDS transpose tile ----
        bf16x8 s0, s1;
#pragma unroll
        for (int j = 0; j < 16; ++j) {
            float vn = v[j] + (acc[j] - v[j]) * 0.5f;
            bool s = (vn >= 0.5f);
            v[j] = s ? 0.f : vn;
            bf16_t sp = s ? (bf16_t)1.0f : (bf16_t)0.0f;
            if (j < 8) s0[j] = sp; else s1[j - 8] = sp;
        }
        *(bf16x8*)&ot[dq][sh]     = s0;
        *(bf16x8*)&ot[dq][sh + 8] = s1;
        __syncthreads();

        // ---- write OsT rows (n', 16 consecutive c per thread) ----
        {
            const int nw = tid >> 2, cg = tid & 3;
            bf16x8 o0, o1;
#pragma unroll
            for (int k = 0; k < 8; ++k) o0[k] = ot[cg * 16 + k][nw];
#pragma unroll
            for (int k = 0; k < 8; ++k) o1[k] = ot[cg * 16 + 8 + k][nw];
            bf16_t* dst = osT + (size_t)(tb * N_ + nc * 64 + nw) * C_ + h * 64 + cg * 16;
            *(bf16x8*)dst = o0;
            *(bf16x8*)(dst + 8) = o1;
        }
        __syncthreads();   // before next t overwrites Kb/Vb/Qw/M2f/ot
    }
}

// =====================================================================
extern "C" void kernel_launch(void* const* d_in, const int* in_sizes, int n_in,
                              void* d_out, int out_size, void* d_ws, size_t ws_size,
                              hipStream_t stream)
{
    const float* x   = (const float*)d_in[0];
    const float* Wq  = (const float*)d_in[1];
    const float* qg  = (const float*)d_in[2];
    const float* qb  = (const float*)d_in[3];
    const float* qm  = (const float*)d_in[4];
    const float* qv  = (const float*)d_in[5];
    const float* Wk  = (const float*)d_in[6];
    const float* kg  = (const float*)d_in[7];
    const float* kb  = (const float*)d_in[8];
    const float* km  = (const float*)d_in[9];
    const float* kv  = (const float*)d_in[10];
    const float* Wv  = (const float*)d_in[11];
    const float* vg  = (const float*)d_in[12];
    const float* vb  = (const float*)d_in[13];
    const float* vm  = (const float*)d_in[14];
    const float* vv  = (const float*)d_in[15];
    const float* Wp  = (const float*)d_in[16];
    const float* bp  = (const float*)d_in[17];
    const float* pg  = (const float*)d_in[18];
    const float* pb  = (const float*)d_in[19];
    const float* pm  = (const float*)d_in[20];
    const float* pv  = (const float*)d_in[21];

    char* ws = (char*)d_ws;
    bf16_t* xsT    = (bf16_t*)(ws + XS_OFF);
    bf16_t* Ahi    = (bf16_t*)(ws + AHI_OFF);
    bf16_t* Alo    = (bf16_t*)(ws + ALO_OFF);
    bf16_t* Phi    = (bf16_t*)(ws + PHI_OFF);
    bf16_t* Plo    = (bf16_t*)(ws + PLO_OFF);
    float*  scv    = (float*)(ws + SC_OFF);
    float*  shv    = (float*)(ws + SH_OFF);
    float*  psc    = (float*)(ws + PSC_OFF);
    float*  psh    = (float*)(ws + PSH_OFF);
    float*  y1     = (float*)(ws + Y1_OFF);
    u64*    qbits  = (u64*)(ws + QB_OFF);
    u64*    kbits  = (u64*)(ws + KB_OFF);
    u64*    vbits  = (u64*)(ws + VB_OFF);
    bf16_t* osT    = (bf16_t*)(ws + OST_OFF);
    float*  out    = (float*)d_out;

    prep_kernel<<<dim3(3072), dim3(256), 0, stream>>>(
        Wq, Wk, Wv, Wp, qg, qb, qm, qv, kg, kb, km, kv, vg, vb, vm, vv,
        bp, pg, pb, pm, pv, Ahi, Alo, Phi, Plo, scv, shv, psc, psh);

    lif_x_kernel<<<dim3(16, 8, 4), dim3(256), 0, stream>>>(x, xsT);

    // three qkv branches: GEMM(+BN) -> LIF -> spike bits  (y1 reused)
    u64* bits[3] = {qbits, kbits, vbits};
    for (int br = 0; br < 3; ++br) {
        gemm_spk<0><<<dim3(128, 4), dim3(256), 0, stream>>>(
            Ahi + (size_t)br * 512 * 512, Alo + (size_t)br * 512 * 512,
            xsT, scv + br * 512, shv + br * 512, y1);
        lif_bits_kernel<<<dim3(4, 4, 512), dim3(256), 0, stream>>>(y1, bits[br]);
    }

    attn_kernel<<<dim3(16, 8, 4), dim3(256), 0, stream>>>(qbits, kbits, vbits, osT);

    gemm_spk<1><<<dim3(128, 4), dim3(256), 0, stream>>>(Phi, Plo, osT, psc, psh, out);

    (void)in_sizes; (void)n_in; (void)out_size; (void)ws_size;
}

// Round 2
// 269.067 us; speedup vs baseline: 1.2830x; 1.2830x over previous
//
#include <hip/hip_runtime.h>
#include <hip/hip_bf16.h>
#include <stdint.h>

// ---------------- problem constants ----------------
#define T_  4
#define B_  4
#define C_  512
#define N_  1024       // H*W
#define NH_ 8
#define HD_ 64
#define NP_ 16384      // T*B*N  (columns of the big GEMMs)
#define EPS_ 1e-5f

typedef __bf16 bf16_t;
typedef __bf16 bf16x8 __attribute__((ext_vector_type(8)));
typedef float  f32x4  __attribute__((ext_vector_type(4)));
typedef unsigned long long u64;

// ---------------- workspace layout (bytes) ----------------
// total = 75,513,856 B (~72 MB).  osT ALIASES xsT (xsT dead after 3rd GEMM).
#define XS_OFF   0ULL                      // bf16 XsT[16384][512] (x spikes, T-major cols) ; later osT
#define AHI_OFF  16777216ULL               // bf16 [1536][512]  stacked Wq/Wk/Wv hi
#define ALO_OFF  18350080ULL               // bf16 [1536][512]  lo
#define PHI_OFF  19922944ULL               // bf16 [512][512]   Wp hi
#define PLO_OFF  20447232ULL               // bf16 [512][512]   Wp lo
#define SC_OFF   20971520ULL               // f32 [1536] BN scale (stacked q,k,v)
#define SH_OFF   20977664ULL               // f32 [1536] BN shift
#define PSC_OFF  20983808ULL               // f32 [512]
#define PSH_OFF  20985856ULL               // f32 [512]  (includes bp folded)
#define Y1_OFF   20987904ULL               // f32 [512][16384]  (one branch at a time)
#define QS_OFF   54542336ULL               // bf16 qsT[16384][512]  q spikes
#define KB_OFF   71319552ULL               // u64 [16][8][64][16] k spike bits (bits over n)
#define VB_OFF   72368128ULL               // u64 [16][8][64][16]
#define M2H_OFF  73416704ULL               // bf16 M2T_hi[128][64][64]  (tb*8+h major)
#define M2L_OFF  74465280ULL               // bf16 M2T_lo[128][64][64]

// =====================================================================
// K0: weight split (hi/lo bf16) + BN constant folding
// =====================================================================
__global__ __launch_bounds__(256) void prep_kernel(
    const float* __restrict__ Wq, const float* __restrict__ Wk,
    const float* __restrict__ Wv, const float* __restrict__ Wp,
    const float* __restrict__ qg, const float* __restrict__ qb, const float* __restrict__ qm, const float* __restrict__ qv,
    const float* __restrict__ kg, const float* __restrict__ kb, const float* __restrict__ km, const float* __restrict__ kv,
    const float* __restrict__ vg, const float* __restrict__ vb, const float* __restrict__ vm, const float* __restrict__ vv,
    const float* __restrict__ bp,
    const float* __restrict__ pg, const float* __restrict__ pb, const float* __restrict__ pm, const float* __restrict__ pv,
    bf16_t* __restrict__ Ahi, bf16_t* __restrict__ Alo,
    bf16_t* __restrict__ Phi, bf16_t* __restrict__ Plo,
    float* __restrict__ scale, float* __restrict__ shift,
    float* __restrict__ pscale, float* __restrict__ pshift)
{
    const int i0 = blockIdx.x * 256 + threadIdx.x;
    const int stride = gridDim.x * 256;
    for (int idx = i0; idx < 1536 * 512; idx += stride) {
        int r = idx >> 9;
        int br = r >> 9;
        const float* W = (br == 0) ? Wq : (br == 1) ? Wk : Wv;
        float w = W[((r & 511) << 9) + (idx & 511)];
        bf16_t h = (bf16_t)w;
        Ahi[idx] = h;
        Alo[idx] = (bf16_t)(w - (float)h);
    }
    for (int idx = i0; idx < 512 * 512; idx += stride) {
        float w = Wp[idx];
        bf16_t h = (bf16_t)w;
        Phi[idx] = h;
        Plo[idx] = (bf16_t)(w - (float)h);
    }
    for (int idx = i0; idx < 1536; idx += stride) {
        int br = idx >> 9, d = idx & 511;
        const float* g  = (br == 0) ? qg : (br == 1) ? kg : vg;
        const float* bb = (br == 0) ? qb : (br == 1) ? kb : vb;
        const float* mm = (br == 0) ? qm : (br == 1) ? km : vm;
        const float* vr = (br == 0) ? qv : (br == 1) ? kv : vv;
        float sc = g[d] / sqrtf(vr[d] + EPS_);
        scale[idx] = sc;
        shift[idx] = bb[d] - mm[d] * sc;
    }
    for (int idx = i0; idx < 512; idx += stride) {
        float sc = pg[idx] / sqrtf(pv[idx] + EPS_);
        pscale[idx] = sc;
        pshift[idx] = (bp[idx] - pm[idx]) * sc + pb[idx];
    }
}

// =====================================================================
// K1: proj_lif on x -> spikes, stored transposed XsT[n'][c] bf16
// =====================================================================
__global__ __launch_bounds__(256) void lif_x_kernel(const float* __restrict__ x,
                                                    bf16_t* __restrict__ xsT)
{
    const int tid = threadIdx.x;
    const int n  = blockIdx.x * 64 + (tid & 63);
    const int c0 = blockIdx.y * 64 + (tid >> 6) * 16;
    const int b  = blockIdx.z;
    float v[16];
#pragma unroll
    for (int k = 0; k < 16; ++k) v[k] = 0.f;

    for (int t = 0; t < T_; ++t) {
        bf16x8 s0, s1;
#pragma unroll
        for (int k = 0; k < 16; ++k) {
            float xv = x[(size_t)((t * B_ + b) * C_ + (c0 + k)) * N_ + n];
            float vn = v[k] + (xv - v[k]) * 0.5f;           // tau = 2
            bool s = (vn >= 1.0f);
            v[k] = s ? 0.0f : vn;                           // hard reset
            bf16_t sp = s ? (bf16_t)1.0f : (bf16_t)0.0f;
            if (k < 8) s0[k] = sp; else s1[k - 8] = sp;
        }
        bf16_t* dst = xsT + (size_t)((t * B_ + b) * N_ + n) * C_ + c0;
        *(bf16x8*)dst = s0;
        *(bf16x8*)(dst + 8) = s1;
    }
}

// =====================================================================
// GEMM (m97 structure, unchanged from round 1 — passed exact)
// MODE 0: out f32 [512][16384] with BN fused
// MODE 1: out = d_out [T*B][C][N]
// =====================================================================
template <int MODE>
__global__ __launch_bounds__(256) void gemm_spk(
    const bf16_t* __restrict__ Ahi, const bf16_t* __restrict__ Alo,
    const bf16_t* __restrict__ Bm,
    const float* __restrict__ scale, const float* __restrict__ shift,
    float* __restrict__ out)
{
    __shared__ bf16_t AsH[128 * 32];
    __shared__ bf16_t AsL[128 * 32];
    __shared__ bf16_t Bs [128 * 32];

    const int tid  = threadIdx.x;
    const int lane = tid & 63;
    const int wv   = tid >> 6;
    const int wr   = wv >> 1, wc = wv & 1;
    const int m0   = blockIdx.y * 128;
    const int n0   = blockIdx.x * 128;

    f32x4 acc[4][4];
#pragma unroll
    for (int i = 0; i < 4; ++i)
#pragma unroll
        for (int j = 0; j < 4; ++j) acc[i][j] = f32x4{0.f, 0.f, 0.f, 0.f};

    const int frow = lane & 15;
    const int koff = (lane >> 4) << 3;

    for (int kk = 0; kk < 512; kk += 32) {
#pragma unroll
        for (int s = 0; s < 2; ++s) {
            int idx = s * 256 + tid;
            int row = idx >> 2;
            int kc  = (idx & 3) << 3;
            size_t goffA = (size_t)(m0 + row) * 512 + kk + kc;
            size_t goffB = (size_t)(n0 + row) * 512 + kk + kc;
            int ldsoff = (s * 256 + wv * 64) * 8;
            __builtin_amdgcn_global_load_lds((const __attribute__((address_space(1))) void*)(Ahi + goffA),
                                             (__attribute__((address_space(3))) void*)(AsH + ldsoff), 16, 0, 0);
            __builtin_amdgcn_global_load_lds((const __attribute__((address_space(1))) void*)(Alo + goffA),
                                             (__attribute__((address_space(3))) void*)(AsL + ldsoff), 16, 0, 0);
            __builtin_amdgcn_global_load_lds((const __attribute__((address_space(1))) void*)(Bm + goffB),
                                             (__attribute__((address_space(3))) void*)(Bs + ldsoff), 16, 0, 0);
        }
        __syncthreads();

        bf16x8 ah[4], al[4], bb[4];
#pragma unroll
        for (int mi = 0; mi < 4; ++mi) {
            ah[mi] = *(const bf16x8*)&AsH[(wr * 64 + mi * 16 + frow) * 32 + koff];
            al[mi] = *(const bf16x8*)&AsL[(wr * 64 + mi * 16 + frow) * 32 + koff];
        }
#pragma unroll
        for (int ni = 0; ni < 4; ++ni)
            bb[ni] = *(const bf16x8*)&Bs[(wc * 64 + ni * 16 + frow) * 32 + koff];

#pragma unroll
        for (int mi = 0; mi < 4; ++mi)
#pragma unroll
            for (int ni = 0; ni < 4; ++ni) {
                acc[mi][ni] = __builtin_amdgcn_mfma_f32_16x16x32_bf16(ah[mi], bb[ni], acc[mi][ni], 0, 0, 0);
                acc[mi][ni] = __builtin_amdgcn_mfma_f32_16x16x32_bf16(al[mi], bb[ni], acc[mi][ni], 0, 0, 0);
            }
        __syncthreads();
    }

#pragma unroll
    for (int mi = 0; mi < 4; ++mi)
#pragma unroll
        for (int ni = 0; ni < 4; ++ni)
#pragma unroll
            for (int r = 0; r < 4; ++r) {
                int gr = m0 + wr * 64 + mi * 16 + (lane >> 4) * 4 + r;
                int gc = n0 + wc * 64 + ni * 16 + (lane & 15);
                float vout = acc[mi][ni][r] * scale[gr] + shift[gr];
                if (MODE == 0) {
                    out[(size_t)gr * NP_ + gc] = vout;
                } else {
                    int tb = gc >> 10, nn = gc & 1023;
                    out[((size_t)(tb * C_ + gr)) * N_ + nn] = vout;
                }
            }
}

// =====================================================================
// K3: LIF over t + ballot bit-pack (K and V branches only)
// =====================================================================
__global__ __launch_bounds__(256) void lif_bits_kernel(const float* __restrict__ Y1,
                                                       u64* __restrict__ dst)
{
    const int tid = threadIdx.x;
    const int n = blockIdx.x * 256 + tid;
    const int b = blockIdx.y;
    const int r = blockIdx.z;            // channel 0..511 within branch
    const int h = r >> 6, d = r & 63;
    const int w = n >> 6;
    const int lane = tid & 63;

    const float* src = Y1 + (size_t)r * NP_;
    float v = 0.f;
    for (int t = 0; t < T_; ++t) {
        float val = src[((t * B_ + b) << 10) + n];
        v = v + (val - v) * 0.5f;
        bool s = (v >= 1.0f);
        if (s) v = 0.f;
        u64 mask = __ballot(s);
        if (lane == 0)
            dst[((size_t)((t * B_ + b) * NH_ + h) * 64 + d) * 16 + w] = mask;
    }
}

// =====================================================================
// K3q: LIF over t on q branch -> bf16 spikes, transposed to qsT[n'][c]
//  block: (n-tile 64, c-tile 64, b); thread owns (16 c, 1 n) across t.
// =====================================================================
__global__ __launch_bounds__(256) void lif_spk_q(const float* __restrict__ Y1,
                                                 bf16_t* __restrict__ qsT)
{
    __shared__ bf16_t ldt[64][72];       // [n_local][c_local], 144B rows (16B-mult)
    const int tid = threadIdx.x;
    const int n0 = blockIdx.x * 64;
    const int c0 = blockIdx.y * 64;
    const int b  = blockIdx.z;
    const int nl = tid & 63;
    const int q4 = tid >> 6;

    float v[16];
#pragma unroll
    for (int k = 0; k < 16; ++k) v[k] = 0.f;

    for (int t = 0; t < T_; ++t) {
        const int tb = t * B_ + b;
        bf16_t sp[16];
#pragma unroll
        for (int k = 0; k < 16; ++k) {
            int cl = q4 * 16 + k;
            float val = Y1[(size_t)(c0 + cl) * NP_ + (tb << 10) + n0 + nl];
            float vn = v[k] + (val - v[k]) * 0.5f;
            bool s = (vn >= 1.0f);
            v[k] = s ? 0.f : vn;
            sp[k] = s ? (bf16_t)1.0f : (bf16_t)0.0f;
        }
        __syncthreads();                 // prev iteration's readers done
#pragma unroll
        for (int k = 0; k < 16; ++k) ldt[nl][q4 * 16 + k] = sp[k];
        __syncthreads();
#pragma unroll
        for (int w = 0; w < 2; ++w) {
            int id = w * 256 + tid;
            int row = id >> 3;           // n_local
            int cg  = (id & 7) * 8;      // c chunk
            *(bf16x8*)&qsT[(size_t)((tb << 10) + n0 + row) * C_ + c0 + cg] =
                *(const bf16x8*)&ldt[row][cg];
        }
    }
}

// =====================================================================
// K4: M2T = (K^T V)^T * 0.125, exact hi/lo bf16 split.  One block per (tb,h).
//  M2T[d2][d1] = 0.125 * sum_n k[n][d1] v[n][d2]  (popcount over bit-words)
// =====================================================================
__global__ __launch_bounds__(256) void m2t_kernel(const u64* __restrict__ kbit,
                                                  const u64* __restrict__ vbit,
                                                  bf16_t* __restrict__ m2h,
                                                  bf16_t* __restrict__ m2l)
{
    __shared__ u64 Kb[64][17];
    __shared__ u64 Vb[64][17];
    __shared__ float M2f[64][64];        // [d1][d2]
    const int tid = threadIdx.x;
    const int h  = blockIdx.x;
    const int tb = blockIdx.y;

    const u64* kbase = kbit + (size_t)(tb * NH_ + h) * 1024;
    const u64* vbase = vbit + (size_t)(tb * NH_ + h) * 1024;
    for (int i = tid; i < 1024; i += 256) {
        Kb[i >> 4][i & 15] = kbase[i];
        Vb[i >> 4][i & 15] = vbase[i];
    }
    __syncthreads();

    const int d1 = tid >> 2, l2 = tid & 3;
    int cnt[16];
#pragma unroll
    for (int jj = 0; jj < 16; ++jj) cnt[jj] = 0;
    for (int w = 0; w < 16; ++w) {
        u64 kw = Kb[d1][w];
#pragma unroll
        for (int jj = 0; jj < 16; ++jj)
            cnt[jj] += __popcll(kw & Vb[l2 + 4 * jj][w]);
    }
#pragma unroll
    for (int jj = 0; jj < 16; ++jj)
        M2f[d1][l2 + 4 * jj] = (float)cnt[jj] * 0.125f;
    __syncthreads();

    // write M2T[d2][d1] hi/lo: thread owns 16 contiguous outputs (row d2=tid>>2)
    const int d2 = tid >> 2, d1b = (tid & 3) * 16;
    bf16x8 h0, h1, l0, l1;
#pragma unroll
    for (int j = 0; j < 16; ++j) {
        float m = M2f[d1b + j][d2];
        bf16_t hi = (bf16_t)m;
        bf16_t lo = (bf16_t)(m - (float)hi);
        if (j < 8) { h0[j] = hi; l0[j] = lo; } else { h1[j - 8] = hi; l1[j - 8] = lo; }
    }
    size_t base = (size_t)(tb * NH_ + h) * 4096 + tid * 16;
    *(bf16x8*)&m2h[base]     = h0;
    *(bf16x8*)&m2h[base + 8] = h1;
    *(bf16x8*)&m2l[base]     = l0;
    *(bf16x8*)&m2l[base + 8] = l1;
}

// =====================================================================
// K5: O^T[d][n] = sum_d1 M2T[d][d1] * Q[n][d1]  via MFMA (exact),
//     fused attn-LIF (v_th=0.5) with state in registers across the t-loop.
//  grid (nt=8, h=8, b=4); block 256 = 4 waves; per-block tile 64d x 128n.
// =====================================================================
__global__ __launch_bounds__(256) void o_kernel(const bf16_t* __restrict__ qsT,
                                                const bf16_t* __restrict__ m2h,
                                                const bf16_t* __restrict__ m2l,
                                                bf16_t* __restrict__ osT)
{
    __shared__ bf16_t Ah[64][72];
    __shared__ bf16_t Al[64][72];
    __shared__ bf16_t Bq[128][72];

    const int tid  = threadIdx.x;
    const int lane = tid & 63;
    const int wv   = tid >> 6;
    const int nt = blockIdx.x, h = blockIdx.y, b = blockIdx.z;
    const int n0 = nt * 128;
    const int frow = lane & 15;
    const int g    = lane >> 4;

    float vst[4][2][4];
#pragma unroll
    for (int mi = 0; mi < 4; ++mi)
#pragma unroll
        for (int ni = 0; ni < 2; ++ni)
#pragma unroll
            for (int r = 0; r < 4; ++r) vst[mi][ni][r] = 0.f;

    for (int t = 0; t < T_; ++t) {
        const int tb = t * B_ + b;
        __syncthreads();                 // prev iteration's frag reads done
        {   // stage M2T hi/lo (64x64)
            int row = tid >> 2, col = (tid & 3) * 16;
            size_t gbase = (size_t)(tb * NH_ + h) * 4096 + row * 64 + col;
            *(bf16x8*)&Ah[row][col]     = *(const bf16x8*)&m2h[gbase];
            *(bf16x8*)&Ah[row][col + 8] = *(const bf16x8*)&m2h[gbase + 8];
            *(bf16x8*)&Al[row][col]     = *(const bf16x8*)&m2l[gbase];
            *(bf16x8*)&Al[row][col + 8] = *(const bf16x8*)&m2l[gbase + 8];
        }
#pragma unroll
        for (int w = 0; w < 4; ++w) {    // stage Q tile (128 rows x 64 cols)
            int id = w * 256 + tid;
            int row = id >> 3, cg = (id & 7) * 8;
            *(bf16x8*)&Bq[row][cg] =
                *(const bf16x8*)&qsT[(size_t)((tb << 10) + n0 + row) * C_ + h * 64 + cg];
        }
        __syncthreads();

        bf16x8 afh[4][2], afl[4][2], bfq[2][2];
#pragma unroll
        for (int mi = 0; mi < 4; ++mi)
#pragma unroll
            for (int ks = 0; ks < 2; ++ks) {
                afh[mi][ks] = *(const bf16x8*)&Ah[mi * 16 + frow][ks * 32 + g * 8];
                afl[mi][ks] = *(const bf16x8*)&Al[mi * 16 + frow][ks * 32 + g * 8];
            }
#pragma unroll
        for (int ni = 0; ni < 2; ++ni)
#pragma unroll
            for (int ks = 0; ks < 2; ++ks)
                bfq[ni][ks] = *(const bf16x8*)&Bq[wv * 32 + ni * 16 + frow][ks * 32 + g * 8];

        f32x4 acc[4][2];
#pragma unroll
        for (int mi = 0; mi < 4; ++mi)
#pragma unroll
            for (int ni = 0; ni < 2; ++ni) acc[mi][ni] = f32x4{0.f, 0.f, 0.f, 0.f};

#pragma unroll
        for (int ks = 0; ks < 2; ++ks)
#pragma unroll
            for (int mi = 0; mi < 4; ++mi)
#pragma unroll
                for (int ni = 0; ni < 2; ++ni) {
                    acc[mi][ni] = __builtin_amdgcn_mfma_f32_16x16x32_bf16(afh[mi][ks], bfq[ni][ks], acc[mi][ni], 0, 0, 0);
                    acc[mi][ni] = __builtin_amdgcn_mfma_f32_16x16x32_bf16(afl[mi][ks], bfq[ni][ks], acc[mi][ni], 0, 0, 0);
                }

        // LIF (v_th=0.5) + spike store: row d = mi*16+g*4+r, col n = wv*32+ni*16+frow
#pragma unroll
        for (int mi = 0; mi < 4; ++mi)
#pragma unroll
            for (int ni = 0; ni < 2; ++ni) {
                ushort4 pk;
                unsigned short* pp = &pk.x;
#pragma unroll
                for (int r = 0; r < 4; ++r) {
                    float o = acc[mi][ni][r];
                    float vn = vst[mi][ni][r] + (o - vst[mi][ni][r]) * 0.5f;
                    bool s = (vn >= 0.5f);
                    vst[mi][ni][r] = s ? 0.f : vn;
                    pp[r] = s ? 0x3F80 : 0;          // bf16 1.0 / 0.0
                }
                size_t off = (size_t)((tb << 10) + n0 + wv * 32 + ni * 16 + frow) * C_
                           + h * 64 + mi * 16 + g * 4;
                *(ushort4*)&osT[off] = pk;
            }
    }
}

// =====================================================================
extern "C" void kernel_launch(void* const* d_in, const int* in_sizes, int n_in,
                              void* d_out, int out_size, void* d_ws, size_t ws_size,
                              hipStream_t stream)
{
    const float* x   = (const float*)d_in[0];
    const float* Wq  = (const float*)d_in[1];
    const float* qg  = (const float*)d_in[2];
    const float* qb  = (const float*)d_in[3];
    const float* qm  = (const float*)d_in[4];
    const float* qv  = (const float*)d_in[5];
    const float* Wk  = (const float*)d_in[6];
    const float* kg  = (const float*)d_in[7];
    const float* kb  = (const float*)d_in[8];
    const float* km  = (const float*)d_in[9];
    const float* kv  = (const float*)d_in[10];
    const float* Wv  = (const float*)d_in[11];
    const float* vg  = (const float*)d_in[12];
    const float* vb  = (const float*)d_in[13];
    const float* vm  = (const float*)d_in[14];
    const float* vv  = (const float*)d_in[15];
    const float* Wp  = (const float*)d_in[16];
    const float* bp  = (const float*)d_in[17];
    const float* pg  = (const float*)d_in[18];
    const float* pb  = (const float*)d_in[19];
    const float* pm  = (const float*)d_in[20];
    const float* pv  = (const float*)d_in[21];

    char* ws = (char*)d_ws;
    bf16_t* xsT    = (bf16_t*)(ws + XS_OFF);
    bf16_t* Ahi    = (bf16_t*)(ws + AHI_OFF);
    bf16_t* Alo    = (bf16_t*)(ws + ALO_OFF);
    bf16_t* Phi    = (bf16_t*)(ws + PHI_OFF);
    bf16_t* Plo    = (bf16_t*)(ws + PLO_OFF);
    float*  scv    = (float*)(ws + SC_OFF);
    float*  shv    = (float*)(ws + SH_OFF);
    float*  psc    = (float*)(ws + PSC_OFF);
    float*  psh    = (float*)(ws + PSH_OFF);
    float*  y1     = (float*)(ws + Y1_OFF);
    bf16_t* qsT    = (bf16_t*)(ws + QS_OFF);
    u64*    kbits  = (u64*)(ws + KB_OFF);
    u64*    vbits  = (u64*)(ws + VB_OFF);
    bf16_t* m2h    = (bf16_t*)(ws + M2H_OFF);
    bf16_t* m2l    = (bf16_t*)(ws + M2L_OFF);
    bf16_t* osT    = (bf16_t*)(ws + XS_OFF);   // ALIAS: xsT dead after 3rd branch GEMM
    float*  out    = (float*)d_out;

    prep_kernel<<<dim3(3072), dim3(256), 0, stream>>>(
        Wq, Wk, Wv, Wp, qg, qb, qm, qv, kg, kb, km, kv, vg, vb, vm, vv,
        bp, pg, pb, pm, pv, Ahi, Alo, Phi, Plo, scv, shv, psc, psh);

    lif_x_kernel<<<dim3(16, 8, 4), dim3(256), 0, stream>>>(x, xsT);

    // Q branch: GEMM -> bf16 spikes (transposed)
    gemm_spk<0><<<dim3(128, 4), dim3(256), 0, stream>>>(
        Ahi, Alo, xsT, scv, shv, y1);
    lif_spk_q<<<dim3(16, 8, 4), dim3(256), 0, stream>>>(y1, qsT);

    // K branch: GEMM -> spike bits
    gemm_spk<0><<<dim3(128, 4), dim3(256), 0, stream>>>(
        Ahi + (size_t)1 * 512 * 512, Alo + (size_t)1 * 512 * 512,
        xsT, scv + 512, shv + 512, y1);
    lif_bits_kernel<<<dim3(4, 4, 512), dim3(256), 0, stream>>>(y1, kbits);

    // V branch: GEMM -> spike bits
    gemm_spk<0><<<dim3(128, 4), dim3(256), 0, stream>>>(
        Ahi + (size_t)2 * 512 * 512, Alo + (size_t)2 * 512 * 512,
        xsT, scv + 1024, shv + 1024, y1);
    lif_bits_kernel<<<dim3(4, 4, 512), dim3(256), 0, stream>>>(y1, vbits);

    // M2T = (K^T V)^T * 0.125, hi/lo split (exact)
    m2t_kernel<<<dim3(8, 16), dim3(256), 0, stream>>>(kbits, vbits, m2h, m2l);

    // O = Q @ M2 + attn-LIF -> spikes (osT aliases xsT)
    o_kernel<<<dim3(8, 8, 4), dim3(256), 0, stream>>>(qsT, m2h, m2l, osT);

    // proj GEMM + BN + bias -> d_out
    gemm_spk<1><<<dim3(128, 4), dim3(256), 0, stream>>>(Phi, Plo, osT, psc, psh, out);

    (void)in_sizes; (void)n_in; (void)out_size; (void)ws_size;
}